// Round 1
// baseline (2694.970 us; speedup 1.0000x reference)
//
#include <hip/hip_runtime.h>

#define BATCH_ 2048
#define IN_    512
#define HID_   1024
#define NL_    30

// ---------------------------------------------------------------------------
// Tiled f32 NT-GEMM:  acc[m][n] = sum_k A[m][k] * B[n][k]
// BM=128, BN=64, BK=16, 256 threads, 8x4 thread tile.
// Epilogues:
//   E_STORE: Co = acc
//   E_C    : Co = 0.1*Gdiag[n] - 1.2*acc          (C = P*||W_n||^2 - (1+2P)*yW^T)
//   E_Z    : Co = A[m][n] - step*(acc + Cb[m][n]) (z = x - step*(x@G + C))
// ---------------------------------------------------------------------------
enum { E_STORE = 0, E_C = 1, E_Z = 2 };

template <int EPI>
__global__ __launch_bounds__(256) void gemm_nt(
    const float* __restrict__ A, const float* __restrict__ B,
    float* __restrict__ Co, int M, int N, int K,
    const float* __restrict__ Gd, const float* __restrict__ Cb,
    const float* __restrict__ step_p) {
  constexpr int BM = 128, BN = 64, BK = 16;
  __shared__ float As[BK][BM + 4];
  __shared__ float Bs[BK][BN + 4];
  const int t = threadIdx.x;
  const int tx = t & 15;        // 16 col-threads * 4 cols
  const int ty = t >> 4;        // 16 row-threads * 8 rows
  const int m0 = blockIdx.y * BM, n0 = blockIdx.x * BN;

  const int alr = t >> 1, alk = (t & 1) * 8;   // A: 2 float4 per thread
  const int blr = t >> 2, blk_ = (t & 3) * 4;  // B: 1 float4 per thread

  const float* Ap = A + (size_t)(m0 + alr) * K + alk;
  const float* Bp = B + (size_t)(n0 + blr) * K + blk_;

  float4 ra0 = *(const float4*)(Ap);
  float4 ra1 = *(const float4*)(Ap + 4);
  float4 rb  = *(const float4*)(Bp);

  float acc[8][4];
#pragma unroll
  for (int i = 0; i < 8; i++)
#pragma unroll
    for (int j = 0; j < 4; j++) acc[i][j] = 0.f;

  const int nt = K / BK;
  for (int kt = 0; kt < nt; ++kt) {
    As[alk + 0][alr] = ra0.x; As[alk + 1][alr] = ra0.y;
    As[alk + 2][alr] = ra0.z; As[alk + 3][alr] = ra0.w;
    As[alk + 4][alr] = ra1.x; As[alk + 5][alr] = ra1.y;
    As[alk + 6][alr] = ra1.z; As[alk + 7][alr] = ra1.w;
    Bs[blk_ + 0][blr] = rb.x; Bs[blk_ + 1][blr] = rb.y;
    Bs[blk_ + 2][blr] = rb.z; Bs[blk_ + 3][blr] = rb.w;
    __syncthreads();
    if (kt + 1 < nt) {  // register prefetch of next k-tile
      ra0 = *(const float4*)(Ap + (kt + 1) * BK);
      ra1 = *(const float4*)(Ap + (kt + 1) * BK + 4);
      rb  = *(const float4*)(Bp + (kt + 1) * BK);
    }
#pragma unroll
    for (int kk = 0; kk < BK; ++kk) {
      float4 a0 = *(const float4*)&As[kk][ty * 8];
      float4 a1 = *(const float4*)&As[kk][ty * 8 + 4];
      float4 bv = *(const float4*)&Bs[kk][tx * 4];
      float a[8] = {a0.x, a0.y, a0.z, a0.w, a1.x, a1.y, a1.z, a1.w};
      float b[4] = {bv.x, bv.y, bv.z, bv.w};
#pragma unroll
      for (int i = 0; i < 8; i++)
#pragma unroll
        for (int j = 0; j < 4; j++) acc[i][j] = fmaf(a[i], b[j], acc[i][j]);
    }
    __syncthreads();
  }

  float stepv = 0.f;
  if constexpr (EPI == E_Z) stepv = *step_p;
  float gd[4];
  if constexpr (EPI == E_C) {
#pragma unroll
    for (int j = 0; j < 4; j++) {
      int n = n0 + tx * 4 + j;
      gd[j] = Gd[(size_t)n * (HID_ + 1)];  // G[n][n] = ||W_n||^2
    }
  }
  const int col = n0 + tx * 4;
#pragma unroll
  for (int i = 0; i < 8; i++) {
    int row = m0 + ty * 8 + i;
    float v[4];
#pragma unroll
    for (int j = 0; j < 4; j++) v[j] = acc[i][j];
    if constexpr (EPI == E_C) {
#pragma unroll
      for (int j = 0; j < 4; j++) v[j] = 0.1f * gd[j] - 1.2f * v[j];
    }
    if constexpr (EPI == E_Z) {
      float4 xv = *(const float4*)(A  + (size_t)row * K    + col);
      float4 cv = *(const float4*)(Cb + (size_t)row * HID_ + col);
      v[0] = xv.x - stepv * (v[0] + cv.x);
      v[1] = xv.y - stepv * (v[1] + cv.y);
      v[2] = xv.z - stepv * (v[2] + cv.z);
      v[3] = xv.w - stepv * (v[3] + cv.w);
    }
    *(float4*)(Co + (size_t)row * N + col) = make_float4(v[0], v[1], v[2], v[3]);
  }
}

// ---------------------------------------------------------------------------
// W transpose: WT[k][h] = W[h][k]   (W: [1024][512] -> WT: [512][1024])
// ---------------------------------------------------------------------------
__global__ __launch_bounds__(256) void transposeW(const float* __restrict__ W,
                                                  float* __restrict__ WT) {
  __shared__ float tile[32][33];
  int bx = blockIdx.x * 32;  // k base (512)
  int by = blockIdx.y * 32;  // h base (1024)
  int tx = threadIdx.x, ty = threadIdx.y;  // 32 x 8
#pragma unroll
  for (int i = 0; i < 32; i += 8)
    tile[ty + i][tx] = W[(size_t)(by + ty + i) * IN_ + bx + tx];
  __syncthreads();
#pragma unroll
  for (int i = 0; i < 32; i += 8)
    WT[(size_t)(bx + ty + i) * HID_ + by + tx] = tile[tx][ty + i];
}

// ---------------------------------------------------------------------------
// Layer 0: z = -step * C   (x_tmp == 0)
// ---------------------------------------------------------------------------
__global__ __launch_bounds__(256) void z0_kern(const float* __restrict__ Cb,
                                               float* __restrict__ z,
                                               const float* __restrict__ step_p) {
  float s = *step_p;
  int i = blockIdx.x * blockDim.x + threadIdx.x;
  float4 c = ((const float4*)Cb)[i];
  ((float4*)z)[i] = make_float4(-s * c.x, -s * c.y, -s * c.z, -s * c.w);
}

// ---------------------------------------------------------------------------
// Sparsemax (exact simplex projection via Michelot) + FISTA momentum.
// One block (256 thr) per row of 1024; row kept in registers as float4.
//   x_new = relu(z - tau),  x_tmp = x_new + mom*(x_new - x_old), x_old = x_new
// ---------------------------------------------------------------------------
__device__ __forceinline__ void breduce2(float& a, float& b, float* lds, int t) {
#pragma unroll
  for (int o = 32; o; o >>= 1) {
    a += __shfl_down(a, o, 64);
    b += __shfl_down(b, o, 64);
  }
  int w = t >> 6;
  if ((t & 63) == 0) { lds[w * 2] = a; lds[w * 2 + 1] = b; }
  __syncthreads();
  a = lds[0] + lds[2] + lds[4] + lds[6];
  b = lds[1] + lds[3] + lds[5] + lds[7];
  __syncthreads();
}

__global__ __launch_bounds__(256) void sparsemax_mom(
    const float* __restrict__ z, float* __restrict__ xold,
    float* __restrict__ xtmp, float mom) {
  __shared__ float red[8];
  const int row = blockIdx.x;
  const int t = threadIdx.x;
  float4 v = ((const float4*)(z + (size_t)row * HID_))[t];

  float a = v.x + v.y + v.z + v.w, b = 0.f;
  breduce2(a, b, red, t);
  float tau = (a - 1.0f) * (1.0f / (float)HID_);
  int cprev = HID_ + 1024;  // sentinel
  for (int it = 0; it < 64; ++it) {
    float sp = 0.f, cp = 0.f;
    if (v.x > tau) { sp += v.x; cp += 1.f; }
    if (v.y > tau) { sp += v.y; cp += 1.f; }
    if (v.z > tau) { sp += v.z; cp += 1.f; }
    if (v.w > tau) { sp += v.w; cp += 1.f; }
    breduce2(sp, cp, red, t);
    int ci = (int)cp;
    tau = (sp - 1.0f) / cp;
    if (ci == cprev) break;  // support stable -> exact projection found
    cprev = ci;
  }
  float4 xn = make_float4(fmaxf(v.x - tau, 0.f), fmaxf(v.y - tau, 0.f),
                          fmaxf(v.z - tau, 0.f), fmaxf(v.w - tau, 0.f));
  float4 xt4 = xn;
  if (mom > 0.f) {
    float4 xo = ((const float4*)(xold + (size_t)row * HID_))[t];
    xt4.x = xn.x + mom * (xn.x - xo.x);
    xt4.y = xn.y + mom * (xn.y - xo.y);
    xt4.z = xn.z + mom * (xn.z - xo.z);
    xt4.w = xn.w + mom * (xn.w - xo.w);
  }
  ((float4*)(xold + (size_t)row * HID_))[t] = xn;
  ((float4*)(xtmp + (size_t)row * HID_))[t] = xt4;
}

// ---------------------------------------------------------------------------
extern "C" void kernel_launch(void* const* d_in, const int* in_sizes, int n_in,
                              void* d_out, int out_size, void* d_ws, size_t ws_size,
                              hipStream_t stream) {
  (void)in_sizes; (void)n_in; (void)out_size; (void)ws_size;
  const float* y      = (const float*)d_in[0];  // [2048,512]
  const float* W      = (const float*)d_in[1];  // [1024,512]
  const float* step_p = (const float*)d_in[2];  // scalar
  float* out = (float*)d_out;                   // [2048,512]

  float* ws = (float*)d_ws;
  float* G  = ws;                    // 1024*1024
  float* Cb = G  + (size_t)HID_ * HID_;          // 2048*1024
  float* z  = Cb + (size_t)BATCH_ * HID_;        // 2048*1024
  float* xt = z  + (size_t)BATCH_ * HID_;        // 2048*1024
  float* xo = xt + (size_t)BATCH_ * HID_;        // 2048*1024
  float* WT = xo + (size_t)BATCH_ * HID_;        // 512*1024

  dim3 blk(256);
  // G = W @ W^T  (symmetric)
  gemm_nt<E_STORE><<<dim3(HID_ / 64, HID_ / 128), blk, 0, stream>>>(
      W, W, G, HID_, HID_, IN_, nullptr, nullptr, nullptr);
  // C = 0.1*diag(G)[n] - 1.2*(y @ W^T)   (P*||y||^2 row-constant dropped:
  //  simplex projection is invariant to per-row constant shifts)
  gemm_nt<E_C><<<dim3(HID_ / 64, BATCH_ / 128), blk, 0, stream>>>(
      y, W, Cb, BATCH_, HID_, IN_, G, nullptr, nullptr);
  // WT for decode
  transposeW<<<dim3(IN_ / 32, HID_ / 32), dim3(32, 8), 0, stream>>>(W, WT);

  // layer 0: x_tmp = 0 -> z = -step*C ; mom = 0
  z0_kern<<<dim3(BATCH_ * HID_ / 4 / 256), blk, 0, stream>>>(Cb, z, step_p);
  sparsemax_mom<<<dim3(BATCH_), blk, 0, stream>>>(z, xo, xt, 0.f);

  for (int l = 1; l < NL_; ++l) {
    // z = x_tmp - step*(x_tmp @ G + C)   (G symmetric -> NT works)
    gemm_nt<E_Z><<<dim3(HID_ / 64, BATCH_ / 128), blk, 0, stream>>>(
        xt, G, z, BATCH_, HID_, HID_, nullptr, Cb, step_p);
    float mom = (float)l / ((float)l + 3.0f);
    sparsemax_mom<<<dim3(BATCH_), blk, 0, stream>>>(z, xo, xt, mom);
  }

  // out = x_new @ W  == x_new @ WT^T
  gemm_nt<E_STORE><<<dim3(IN_ / 64, BATCH_ / 128), blk, 0, stream>>>(
      xo, WT, out, BATCH_, IN_, HID_, nullptr, nullptr, nullptr);
}

// Round 2
// 1029.698 us; speedup vs baseline: 2.6172x; 2.6172x over previous
//
#include <hip/hip_runtime.h>
#include <cstdint>

#define BATCH_ 2048
#define IN_    512
#define HID_   1024
#define NL_    30

typedef _Float16 h8 __attribute__((ext_vector_type(8)));
typedef _Float16 h4 __attribute__((ext_vector_type(4)));
typedef float f4 __attribute__((ext_vector_type(4)));

// ---------------------------------------------------------------------------
// f32 vector-ALU NT-GEMM (kept for the exact-precision prologue/epilogue:
// G = W@W^T, C = 0.1*diag(G) - 1.2*y@W^T, decode = x@W).
// ---------------------------------------------------------------------------
enum { E_STORE = 0, E_C = 1 };

template <int EPI>
__global__ __launch_bounds__(256) void gemm_nt(
    const float* __restrict__ A, const float* __restrict__ B,
    float* __restrict__ Co, int M, int N, int K,
    const float* __restrict__ Gd) {
  constexpr int BM = 128, BN = 64, BK = 16;
  __shared__ float As[BK][BM + 4];
  __shared__ float Bs[BK][BN + 4];
  const int t = threadIdx.x;
  const int tx = t & 15;
  const int ty = t >> 4;
  const int m0 = blockIdx.y * BM, n0 = blockIdx.x * BN;

  const int alr = t >> 1, alk = (t & 1) * 8;
  const int blr = t >> 2, blk_ = (t & 3) * 4;

  const float* Ap = A + (size_t)(m0 + alr) * K + alk;
  const float* Bp = B + (size_t)(n0 + blr) * K + blk_;

  float4 ra0 = *(const float4*)(Ap);
  float4 ra1 = *(const float4*)(Ap + 4);
  float4 rb  = *(const float4*)(Bp);

  float acc[8][4];
#pragma unroll
  for (int i = 0; i < 8; i++)
#pragma unroll
    for (int j = 0; j < 4; j++) acc[i][j] = 0.f;

  const int nt = K / BK;
  for (int kt = 0; kt < nt; ++kt) {
    As[alk + 0][alr] = ra0.x; As[alk + 1][alr] = ra0.y;
    As[alk + 2][alr] = ra0.z; As[alk + 3][alr] = ra0.w;
    As[alk + 4][alr] = ra1.x; As[alk + 5][alr] = ra1.y;
    As[alk + 6][alr] = ra1.z; As[alk + 7][alr] = ra1.w;
    Bs[blk_ + 0][blr] = rb.x; Bs[blk_ + 1][blr] = rb.y;
    Bs[blk_ + 2][blr] = rb.z; Bs[blk_ + 3][blr] = rb.w;
    __syncthreads();
    if (kt + 1 < nt) {
      ra0 = *(const float4*)(Ap + (kt + 1) * BK);
      ra1 = *(const float4*)(Ap + (kt + 1) * BK + 4);
      rb  = *(const float4*)(Bp + (kt + 1) * BK);
    }
#pragma unroll
    for (int kk = 0; kk < BK; ++kk) {
      float4 a0 = *(const float4*)&As[kk][ty * 8];
      float4 a1 = *(const float4*)&As[kk][ty * 8 + 4];
      float4 bv = *(const float4*)&Bs[kk][tx * 4];
      float a[8] = {a0.x, a0.y, a0.z, a0.w, a1.x, a1.y, a1.z, a1.w};
      float b[4] = {bv.x, bv.y, bv.z, bv.w};
#pragma unroll
      for (int i = 0; i < 8; i++)
#pragma unroll
        for (int j = 0; j < 4; j++) acc[i][j] = fmaf(a[i], b[j], acc[i][j]);
    }
    __syncthreads();
  }

  float gd[4];
  if constexpr (EPI == E_C) {
#pragma unroll
    for (int j = 0; j < 4; j++) {
      int n = n0 + tx * 4 + j;
      gd[j] = Gd[(size_t)n * (HID_ + 1)];
    }
  }
  const int col = n0 + tx * 4;
#pragma unroll
  for (int i = 0; i < 8; i++) {
    int row = m0 + ty * 8 + i;
    float v[4];
#pragma unroll
    for (int j = 0; j < 4; j++) v[j] = acc[i][j];
    if constexpr (EPI == E_C) {
#pragma unroll
      for (int j = 0; j < 4; j++) v[j] = 0.1f * gd[j] - 1.2f * v[j];
    }
    *(float4*)(Co + (size_t)row * N + col) = make_float4(v[0], v[1], v[2], v[3]);
  }
}

// ---------------------------------------------------------------------------
// fp16 MFMA GEMM with fused z-epilogue:
//   z = Xf - step * (Ah @ Bh^T + Cb)     (Bh = Gh rows; G symmetric)
// 64x64 tile, BK=64, 4 waves (2x2), each wave 32x32 (2x2 frags 16x16x32).
// LDS double-buffered, staged via global_load_lds(16B) with XOR chunk-swizzle
// applied on the GLOBAL source (rule #21) and on the ds_read address.
// ---------------------------------------------------------------------------
__device__ __forceinline__ void gload_lds16(const void* g, void* l) {
  __builtin_amdgcn_global_load_lds(
      (const __attribute__((address_space(1))) uint32_t*)g,
      (__attribute__((address_space(3))) uint32_t*)l, 16, 0, 0);
}

__global__ __launch_bounds__(256, 4) void hmma_z(
    const _Float16* __restrict__ Ah,   // [M][K]  x_tmp fp16
    const _Float16* __restrict__ Bh,   // [N][K]  Gh (symmetric)
    const float* __restrict__ Xf,      // [M][N]  x_tmp f32
    const float* __restrict__ Cb,      // [M][N]
    float* __restrict__ Z,             // [M][N]
    const float* __restrict__ step_p,
    int M, int N, int K) {
  constexpr int BK = 64;                 // 64 halves = 128 B per tile row
  __shared__ char smem[2 * 16384];       // [buf][ A:8KB | B:8KB ]
  const int t = threadIdx.x;
  const int lane = t & 63;
  const int w = t >> 6;
  const int wm = w >> 1, wn = w & 1;
  const int m0 = blockIdx.y * 64, n0 = blockIdx.x * 64;

  // Staging geometry: tile = 64 rows x 128B. 8 x 1KB segments per tile.
  // Wave w stages segments {2w, 2w+1} of A and of B.
  // Physical byte p = seg*1024 + lane*16 -> row = p>>7, phys chunk = (p>>4)&7.
  // Logical chunk c = phys ^ (row&7)  (inverse swizzle on the global source).
  int srow[2], scol[2];
#pragma unroll
  for (int s2 = 0; s2 < 2; ++s2) {
    int p = (w * 2 + s2) * 1024 + lane * 16;
    int row = p >> 7;
    int c = ((p >> 4) & 7) ^ (row & 7);
    srow[s2] = row;
    scol[s2] = c * 8;  // halves within the row
  }

#define STAGE(buf, kt)                                                        \
  do {                                                                        \
    _Pragma("unroll") for (int s2 = 0; s2 < 2; ++s2) {                        \
      int seg = w * 2 + s2;                                                   \
      const _Float16* ga =                                                    \
          Ah + (size_t)(m0 + srow[s2]) * K + (kt) * BK + scol[s2];            \
      gload_lds16(ga, smem + (buf) * 16384 + seg * 1024);                     \
      const _Float16* gb =                                                    \
          Bh + (size_t)(n0 + srow[s2]) * K + (kt) * BK + scol[s2];            \
      gload_lds16(gb, smem + (buf) * 16384 + 8192 + seg * 1024);              \
    }                                                                         \
  } while (0)

  f4 acc[2][2];
#pragma unroll
  for (int i = 0; i < 2; i++)
#pragma unroll
    for (int j = 0; j < 2; j++) acc[i][j] = (f4){0.f, 0.f, 0.f, 0.f};

  const int fr = lane & 15;   // row within 16-frag (A: M-row, B: N-row)
  const int kg = lane >> 4;   // k-group (8 halves each)

  const int NT = K / BK;
  STAGE(0, 0);
  int cur = 0;
  for (int kt = 0; kt < NT; ++kt) {
    __syncthreads();   // drains vmcnt(0): buf[cur] staged
    if (kt + 1 < NT) STAGE(cur ^ 1, kt + 1);
    const char* Ab = smem + cur * 16384;
    const char* Bb = smem + cur * 16384 + 8192;
#pragma unroll
    for (int kk = 0; kk < 2; ++kk) {  // two k=32 steps
      h8 af[2], bf[2];
#pragma unroll
      for (int i = 0; i < 2; i++) {
        int row = wm * 32 + i * 16 + fr;
        int c = (kk * 4 + kg) ^ (row & 7);
        af[i] = *(const h8*)(Ab + row * 128 + c * 16);
      }
#pragma unroll
      for (int j = 0; j < 2; j++) {
        int row = wn * 32 + j * 16 + fr;
        int c = (kk * 4 + kg) ^ (row & 7);
        bf[j] = *(const h8*)(Bb + row * 128 + c * 16);
      }
#pragma unroll
      for (int i = 0; i < 2; i++)
#pragma unroll
        for (int j = 0; j < 2; j++)
          acc[i][j] =
              __builtin_amdgcn_mfma_f32_16x16x32_f16(af[i], bf[j], acc[i][j], 0, 0, 0);
    }
    __syncthreads();   // all reads of buf[cur] done before next overwrite
    cur ^= 1;
  }
#undef STAGE

  // Epilogue: C/D layout col=lane&15, row=(lane>>4)*4+reg  [m89-verified]
  const float stepv = *step_p;
  const int orow = (lane >> 4) * 4;
  const int ocol = lane & 15;
#pragma unroll
  for (int i = 0; i < 2; i++) {
#pragma unroll
    for (int j = 0; j < 2; j++) {
      int col = n0 + wn * 32 + j * 16 + ocol;
#pragma unroll
      for (int r = 0; r < 4; r++) {
        int row = m0 + wm * 32 + i * 16 + orow + r;
        size_t idx = (size_t)row * N + col;
        Z[idx] = Xf[idx] - stepv * (acc[i][j][r] + Cb[idx]);
      }
    }
  }
}

// ---------------------------------------------------------------------------
// W transpose: WT[k][h] = W[h][k]
// ---------------------------------------------------------------------------
__global__ __launch_bounds__(256) void transposeW(const float* __restrict__ W,
                                                  float* __restrict__ WT) {
  __shared__ float tile[32][33];
  int bx = blockIdx.x * 32;
  int by = blockIdx.y * 32;
  int tx = threadIdx.x, ty = threadIdx.y;
#pragma unroll
  for (int i = 0; i < 32; i += 8)
    tile[ty + i][tx] = W[(size_t)(by + ty + i) * IN_ + bx + tx];
  __syncthreads();
#pragma unroll
  for (int i = 0; i < 32; i += 8)
    WT[(size_t)(bx + ty + i) * HID_ + by + tx] = tile[tx][ty + i];
}

// ---------------------------------------------------------------------------
// f32 -> fp16 convert (for G)
// ---------------------------------------------------------------------------
__global__ __launch_bounds__(256) void f2h(const float* __restrict__ src,
                                           _Float16* __restrict__ dst) {
  int i = blockIdx.x * blockDim.x + threadIdx.x;
  float4 v = ((const float4*)src)[i];
  h4 o;
  o[0] = (_Float16)v.x; o[1] = (_Float16)v.y;
  o[2] = (_Float16)v.z; o[3] = (_Float16)v.w;
  ((h4*)dst)[i] = o;
}

// ---------------------------------------------------------------------------
// Layer 0: z = -step * C
// ---------------------------------------------------------------------------
__global__ __launch_bounds__(256) void z0_kern(const float* __restrict__ Cb,
                                               float* __restrict__ z,
                                               const float* __restrict__ step_p) {
  float s = *step_p;
  int i = blockIdx.x * blockDim.x + threadIdx.x;
  float4 c = ((const float4*)Cb)[i];
  ((float4*)z)[i] = make_float4(-s * c.x, -s * c.y, -s * c.z, -s * c.w);
}

// ---------------------------------------------------------------------------
// Sparsemax (Michelot exact simplex projection) + FISTA momentum.
// Also emits x_tmp as fp16 for the next layer's MFMA A-operand.
// ---------------------------------------------------------------------------
__device__ __forceinline__ void breduce2(float& a, float& b, float* lds, int t) {
#pragma unroll
  for (int o = 32; o; o >>= 1) {
    a += __shfl_down(a, o, 64);
    b += __shfl_down(b, o, 64);
  }
  int w = t >> 6;
  if ((t & 63) == 0) { lds[w * 2] = a; lds[w * 2 + 1] = b; }
  __syncthreads();
  a = lds[0] + lds[2] + lds[4] + lds[6];
  b = lds[1] + lds[3] + lds[5] + lds[7];
  __syncthreads();
}

__global__ __launch_bounds__(256) void sparsemax_mom(
    const float* __restrict__ z, float* __restrict__ xold,
    float* __restrict__ xtmp, _Float16* __restrict__ xth, float mom) {
  __shared__ float red[8];
  const int row = blockIdx.x;
  const int t = threadIdx.x;
  float4 v = ((const float4*)(z + (size_t)row * HID_))[t];

  float a = v.x + v.y + v.z + v.w, b = 0.f;
  breduce2(a, b, red, t);
  float tau = (a - 1.0f) * (1.0f / (float)HID_);
  int cprev = HID_ + 1024;
  for (int it = 0; it < 64; ++it) {
    float sp = 0.f, cp = 0.f;
    if (v.x > tau) { sp += v.x; cp += 1.f; }
    if (v.y > tau) { sp += v.y; cp += 1.f; }
    if (v.z > tau) { sp += v.z; cp += 1.f; }
    if (v.w > tau) { sp += v.w; cp += 1.f; }
    breduce2(sp, cp, red, t);
    int ci = (int)cp;
    tau = (sp - 1.0f) / cp;
    if (ci == cprev) break;
    cprev = ci;
  }
  float4 xn = make_float4(fmaxf(v.x - tau, 0.f), fmaxf(v.y - tau, 0.f),
                          fmaxf(v.z - tau, 0.f), fmaxf(v.w - tau, 0.f));
  float4 xt4 = xn;
  if (mom > 0.f) {
    float4 xo = ((const float4*)(xold + (size_t)row * HID_))[t];
    xt4.x = xn.x + mom * (xn.x - xo.x);
    xt4.y = xn.y + mom * (xn.y - xo.y);
    xt4.z = xn.z + mom * (xn.z - xo.z);
    xt4.w = xn.w + mom * (xn.w - xo.w);
  }
  ((float4*)(xold + (size_t)row * HID_))[t] = xn;
  ((float4*)(xtmp + (size_t)row * HID_))[t] = xt4;
  h4 hv;
  hv[0] = (_Float16)xt4.x; hv[1] = (_Float16)xt4.y;
  hv[2] = (_Float16)xt4.z; hv[3] = (_Float16)xt4.w;
  ((h4*)(xth + (size_t)row * HID_))[t] = hv;
}

// ---------------------------------------------------------------------------
extern "C" void kernel_launch(void* const* d_in, const int* in_sizes, int n_in,
                              void* d_out, int out_size, void* d_ws, size_t ws_size,
                              hipStream_t stream) {
  (void)in_sizes; (void)n_in; (void)out_size; (void)ws_size;
  const float* y      = (const float*)d_in[0];  // [2048,512]
  const float* W      = (const float*)d_in[1];  // [1024,512]
  const float* step_p = (const float*)d_in[2];  // scalar
  float* out = (float*)d_out;                   // [2048,512]

  float* ws = (float*)d_ws;
  float* G  = ws;                               // 1024*1024 f32
  float* Cb = G  + (size_t)HID_ * HID_;         // 2048*1024 f32
  float* z  = Cb + (size_t)BATCH_ * HID_;       // 2048*1024 f32
  float* xt = z  + (size_t)BATCH_ * HID_;       // 2048*1024 f32
  float* xo = xt + (size_t)BATCH_ * HID_;       // 2048*1024 f32
  float* WT = xo + (size_t)BATCH_ * HID_;       // 512*1024  f32
  _Float16* xth = (_Float16*)(WT + (size_t)IN_ * HID_);   // 2048*1024 fp16
  _Float16* Gh  = xth + (size_t)BATCH_ * HID_;            // 1024*1024 fp16

  dim3 blk(256);
  // G = W @ W^T   (exact f32)
  gemm_nt<E_STORE><<<dim3(HID_ / 64, HID_ / 128), blk, 0, stream>>>(
      W, W, G, HID_, HID_, IN_, nullptr);
  f2h<<<dim3(HID_ * HID_ / 4 / 256), blk, 0, stream>>>(G, Gh);
  // C = 0.1*diag(G)[n] - 1.2*(y @ W^T)  (P*||y||^2 row-const dropped: simplex
  // projection is shift-invariant per row)
  gemm_nt<E_C><<<dim3(HID_ / 64, BATCH_ / 128), blk, 0, stream>>>(
      y, W, Cb, BATCH_, HID_, IN_, G);
  transposeW<<<dim3(IN_ / 32, HID_ / 32), dim3(32, 8), 0, stream>>>(W, WT);

  // layer 0: x_tmp = 0 -> z = -step*C ; mom = 0
  z0_kern<<<dim3(BATCH_ * HID_ / 4 / 256), blk, 0, stream>>>(Cb, z, step_p);
  sparsemax_mom<<<dim3(BATCH_), blk, 0, stream>>>(z, xo, xt, xth, 0.f);

  for (int l = 1; l < NL_; ++l) {
    hmma_z<<<dim3(HID_ / 64, BATCH_ / 64), blk, 0, stream>>>(
        xth, Gh, xt, Cb, z, step_p, BATCH_, HID_, HID_);
    float mom = (float)l / ((float)l + 3.0f);
    sparsemax_mom<<<dim3(BATCH_), blk, 0, stream>>>(z, xo, xt, xth, mom);
  }

  // out = x_new @ W == x_new @ WT^T   (exact f32)
  gemm_nt<E_STORE><<<dim3(IN_ / 64, BATCH_ / 128), blk, 0, stream>>>(
      xo, WT, out, BATCH_, IN_, HID_, nullptr);
}

// Round 3
// 801.454 us; speedup vs baseline: 3.3626x; 1.2848x over previous
//
#include <hip/hip_runtime.h>
#include <cstdint>

#define BATCH_ 2048
#define IN_    512
#define HID_   1024
#define NL_    30

typedef _Float16 h8 __attribute__((ext_vector_type(8)));
typedef _Float16 h4 __attribute__((ext_vector_type(4)));
typedef float f4 __attribute__((ext_vector_type(4)));

// ---------------------------------------------------------------------------
// global -> LDS direct staging (16B per lane)
// ---------------------------------------------------------------------------
__device__ __forceinline__ void gload_lds16(const void* g, void* l) {
  __builtin_amdgcn_global_load_lds(
      (const __attribute__((address_space(1))) uint32_t*)g,
      (__attribute__((address_space(3))) uint32_t*)l, 16, 0, 0);
}

// ---------------------------------------------------------------------------
// Generic fp16 NT MFMA GEMM over up to 3 (A,B) pass pairs (split-fp16 trick):
//   acc = sum_p A_p @ B_p^T
// 64x64 tile, BK=64, 4 waves (2x2), wave = 32x32 (2x2 frags of 16x16x32).
// Double-buffered LDS via global_load_lds(16B), XOR chunk-swizzle applied on
// the GLOBAL source and on the ds_read address (both-sides rule).
// Epilogues:
//   H_GH : oh = (fp16)acc ; if (row==col) dG[row] = acc      (G = W@W^T)
//   H_C  : of = 0.1*dG[col] - 1.2*acc                        (C matrix)
//   H_OUT: of = acc                                          (decode)
// ---------------------------------------------------------------------------
enum { H_GH = 0, H_C = 1, H_OUT = 2 };

template <int EPI>
__global__ __launch_bounds__(256, 4) void hgemm_nt(
    const _Float16* __restrict__ A0, const _Float16* __restrict__ B0,
    const _Float16* __restrict__ A1, const _Float16* __restrict__ B1,
    const _Float16* __restrict__ A2, const _Float16* __restrict__ B2,
    int npass, int ktpp,  // K-tiles (of 64) per pass
    float* __restrict__ of, _Float16* __restrict__ oh, float* __restrict__ dG,
    int N, int K) {
  __shared__ char smem[2 * 16384];  // [buf][ A:8KB | B:8KB ]
  const int t = threadIdx.x;
  const int lane = t & 63;
  const int w = t >> 6;
  const int wm = w >> 1, wn = w & 1;
  const int m0 = blockIdx.y * 64, n0 = blockIdx.x * 64;

  // staging geometry (wave w stages segments {2w,2w+1} of A and of B)
  int srow[2], scol[2];
#pragma unroll
  for (int s2 = 0; s2 < 2; ++s2) {
    int p = (w * 2 + s2) * 1024 + lane * 16;
    int row = p >> 7;
    int c = ((p >> 4) & 7) ^ (row & 7);
    srow[s2] = row;
    scol[s2] = c * 8;
  }

  auto selA = [&](int p) { return p == 0 ? A0 : (p == 1 ? A1 : A2); };
  auto selB = [&](int p) { return p == 0 ? B0 : (p == 1 ? B1 : B2); };

  auto stage = [&](int buf, const _Float16* Ab, const _Float16* Bb, int kt) {
#pragma unroll
    for (int s2 = 0; s2 < 2; ++s2) {
      int seg = w * 2 + s2;
      const _Float16* ga = Ab + (size_t)(m0 + srow[s2]) * K + kt * 64 + scol[s2];
      gload_lds16(ga, smem + buf * 16384 + seg * 1024);
      const _Float16* gb = Bb + (size_t)(n0 + srow[s2]) * K + kt * 64 + scol[s2];
      gload_lds16(gb, smem + buf * 16384 + 8192 + seg * 1024);
    }
  };

  f4 acc[2][2];
#pragma unroll
  for (int i = 0; i < 2; i++)
#pragma unroll
    for (int j = 0; j < 2; j++) acc[i][j] = (f4){0.f, 0.f, 0.f, 0.f};

  const int fr = lane & 15;
  const int kg = lane >> 4;

  const int NTtot = npass * ktpp;
  stage(0, selA(0), selB(0), 0);
  int cur = 0, p = 0, kk = 0;
  for (int tt = 0; tt < NTtot; ++tt) {
    __syncthreads();  // drains vmcnt(0): buf[cur] staged
    int pn = p, kn = kk + 1;
    if (kn == ktpp) { kn = 0; pn = p + 1; }
    if (tt + 1 < NTtot) stage(cur ^ 1, selA(pn), selB(pn), kn);
    const char* Ab = smem + cur * 16384;
    const char* Bb = smem + cur * 16384 + 8192;
#pragma unroll
    for (int ks = 0; ks < 2; ++ks) {
      h8 af[2], bf[2];
#pragma unroll
      for (int i = 0; i < 2; i++) {
        int row = wm * 32 + i * 16 + fr;
        int c = (ks * 4 + kg) ^ (row & 7);
        af[i] = *(const h8*)(Ab + row * 128 + c * 16);
      }
#pragma unroll
      for (int j = 0; j < 2; j++) {
        int row = wn * 32 + j * 16 + fr;
        int c = (ks * 4 + kg) ^ (row & 7);
        bf[j] = *(const h8*)(Bb + row * 128 + c * 16);
      }
#pragma unroll
      for (int i = 0; i < 2; i++)
#pragma unroll
        for (int j = 0; j < 2; j++)
          acc[i][j] =
              __builtin_amdgcn_mfma_f32_16x16x32_f16(af[i], bf[j], acc[i][j], 0, 0, 0);
    }
    __syncthreads();
    cur ^= 1; p = pn; kk = kn;
  }

  // C/D layout: col=lane&15, row=(lane>>4)*4+reg  [m89-verified]
  const int orow = (lane >> 4) * 4;
  const int ocol = lane & 15;
#pragma unroll
  for (int i = 0; i < 2; i++) {
#pragma unroll
    for (int j = 0; j < 2; j++) {
      int col = n0 + wn * 32 + j * 16 + ocol;
#pragma unroll
      for (int r = 0; r < 4; r++) {
        int row = m0 + wm * 32 + i * 16 + orow + r;
        size_t idx = (size_t)row * N + col;
        float v = acc[i][j][r];
        if constexpr (EPI == H_GH) {
          oh[idx] = (_Float16)v;
          if (row == col) dG[row] = v;
        }
        if constexpr (EPI == H_C) of[idx] = 0.1f * dG[col] - 1.2f * v;
        if constexpr (EPI == H_OUT) of[idx] = v;
      }
    }
  }
}

// ---------------------------------------------------------------------------
// fp16 MFMA GEMM with fused z-epilogue (iteration kernel, unchanged):
//   z = Xf - step * (Ah @ Bh^T + Cb)
// ---------------------------------------------------------------------------
__global__ __launch_bounds__(256, 4) void hmma_z(
    const _Float16* __restrict__ Ah, const _Float16* __restrict__ Bh,
    const float* __restrict__ Xf, const float* __restrict__ Cb,
    float* __restrict__ Z, const float* __restrict__ step_p,
    int M, int N, int K) {
  __shared__ char smem[2 * 16384];
  const int t = threadIdx.x;
  const int lane = t & 63;
  const int w = t >> 6;
  const int wm = w >> 1, wn = w & 1;
  const int m0 = blockIdx.y * 64, n0 = blockIdx.x * 64;

  int srow[2], scol[2];
#pragma unroll
  for (int s2 = 0; s2 < 2; ++s2) {
    int p = (w * 2 + s2) * 1024 + lane * 16;
    int row = p >> 7;
    int c = ((p >> 4) & 7) ^ (row & 7);
    srow[s2] = row;
    scol[s2] = c * 8;
  }

#define STAGE(buf, kt)                                                        \
  do {                                                                        \
    _Pragma("unroll") for (int s2 = 0; s2 < 2; ++s2) {                        \
      int seg = w * 2 + s2;                                                   \
      const _Float16* ga =                                                    \
          Ah + (size_t)(m0 + srow[s2]) * K + (kt) * 64 + scol[s2];            \
      gload_lds16(ga, smem + (buf) * 16384 + seg * 1024);                     \
      const _Float16* gb =                                                    \
          Bh + (size_t)(n0 + srow[s2]) * K + (kt) * 64 + scol[s2];            \
      gload_lds16(gb, smem + (buf) * 16384 + 8192 + seg * 1024);              \
    }                                                                         \
  } while (0)

  f4 acc[2][2];
#pragma unroll
  for (int i = 0; i < 2; i++)
#pragma unroll
    for (int j = 0; j < 2; j++) acc[i][j] = (f4){0.f, 0.f, 0.f, 0.f};

  const int fr = lane & 15;
  const int kg = lane >> 4;

  const int NT = K / 64;
  STAGE(0, 0);
  int cur = 0;
  for (int kt = 0; kt < NT; ++kt) {
    __syncthreads();
    if (kt + 1 < NT) STAGE(cur ^ 1, kt + 1);
    const char* Ab = smem + cur * 16384;
    const char* Bb = smem + cur * 16384 + 8192;
#pragma unroll
    for (int ks = 0; ks < 2; ++ks) {
      h8 af[2], bf[2];
#pragma unroll
      for (int i = 0; i < 2; i++) {
        int row = wm * 32 + i * 16 + fr;
        int c = (ks * 4 + kg) ^ (row & 7);
        af[i] = *(const h8*)(Ab + row * 128 + c * 16);
      }
#pragma unroll
      for (int j = 0; j < 2; j++) {
        int row = wn * 32 + j * 16 + fr;
        int c = (ks * 4 + kg) ^ (row & 7);
        bf[j] = *(const h8*)(Bb + row * 128 + c * 16);
      }
#pragma unroll
      for (int i = 0; i < 2; i++)
#pragma unroll
        for (int j = 0; j < 2; j++)
          acc[i][j] =
              __builtin_amdgcn_mfma_f32_16x16x32_f16(af[i], bf[j], acc[i][j], 0, 0, 0);
    }
    __syncthreads();
    cur ^= 1;
  }
#undef STAGE

  const float stepv = *step_p;
  const int orow = (lane >> 4) * 4;
  const int ocol = lane & 15;
#pragma unroll
  for (int i = 0; i < 2; i++) {
#pragma unroll
    for (int j = 0; j < 2; j++) {
      int col = n0 + wn * 32 + j * 16 + ocol;
#pragma unroll
      for (int r = 0; r < 4; r++) {
        int row = m0 + wm * 32 + i * 16 + orow + r;
        size_t idx = (size_t)row * N + col;
        Z[idx] = Xf[idx] - stepv * (acc[i][j][r] + Cb[idx]);
      }
    }
  }
}

// ---------------------------------------------------------------------------
// f32 -> (hi fp16, lo fp16) split, 4 elems/thread
// ---------------------------------------------------------------------------
__global__ __launch_bounds__(256) void split_hl(const float* __restrict__ s,
                                                _Float16* __restrict__ hi,
                                                _Float16* __restrict__ lo) {
  int i = blockIdx.x * blockDim.x + threadIdx.x;
  float4 v = ((const float4*)s)[i];
  h4 h, l;
  h[0] = (_Float16)v.x; l[0] = (_Float16)(v.x - (float)h[0]);
  h[1] = (_Float16)v.y; l[1] = (_Float16)(v.y - (float)h[1]);
  h[2] = (_Float16)v.z; l[2] = (_Float16)(v.z - (float)h[2]);
  h[3] = (_Float16)v.w; l[3] = (_Float16)(v.w - (float)h[3]);
  ((h4*)hi)[i] = h;
  ((h4*)lo)[i] = l;
}

// ---------------------------------------------------------------------------
// W [1024][512] f32 -> WT hi/lo fp16 [512][1024]
// ---------------------------------------------------------------------------
__global__ __launch_bounds__(256) void transpose_split(
    const float* __restrict__ W, _Float16* __restrict__ WTh,
    _Float16* __restrict__ WTl) {
  __shared__ float tile[32][33];
  int bx = blockIdx.x * 32;  // k base
  int by = blockIdx.y * 32;  // h base
  int tx = threadIdx.x, ty = threadIdx.y;  // 32 x 8
#pragma unroll
  for (int i = 0; i < 32; i += 8)
    tile[ty + i][tx] = W[(size_t)(by + ty + i) * IN_ + bx + tx];
  __syncthreads();
#pragma unroll
  for (int i = 0; i < 32; i += 8) {
    float v = tile[tx][ty + i];
    _Float16 h = (_Float16)v;
    _Float16 l = (_Float16)(v - (float)h);
    WTh[(size_t)(bx + ty + i) * HID_ + by + tx] = h;
    WTl[(size_t)(bx + ty + i) * HID_ + by + tx] = l;
  }
}

// ---------------------------------------------------------------------------
// Sparsemax (Michelot exact simplex projection) + FISTA momentum.
// ONE WAVE PER ROW (16 f32/lane), shfl-only butterfly reductions, no LDS.
// negstep != nullptr => layer 0: v = -(*negstep) * zsrc  (z = -step*C fold).
// ---------------------------------------------------------------------------
__global__ __launch_bounds__(256) void sparsemax_w(
    const float* __restrict__ zsrc, const float* __restrict__ negstep,
    float* __restrict__ xold, float* __restrict__ xtmp,
    _Float16* __restrict__ xth, float mom) {
  const int lane = threadIdx.x & 63;
  const int row = blockIdx.x * 4 + (threadIdx.x >> 6);
  const float4* zr = (const float4*)(zsrc + (size_t)row * HID_);

  float sc = 1.f;
  if (negstep) sc = -(*negstep);

  float4 v[4];
#pragma unroll
  for (int i = 0; i < 4; i++) {
    float4 tv = zr[lane + 64 * i];
    v[i] = make_float4(sc * tv.x, sc * tv.y, sc * tv.z, sc * tv.w);
  }

  float s = 0.f;
#pragma unroll
  for (int i = 0; i < 4; i++) s += v[i].x + v[i].y + v[i].z + v[i].w;
#pragma unroll
  for (int o = 32; o; o >>= 1) s += __shfl_xor(s, o, 64);
  float tau = (s - 1.0f) * (1.0f / (float)HID_);

  int cprev = HID_ + 1024;
  for (int it = 0; it < 64; ++it) {
    float sp = 0.f, cp = 0.f;
#pragma unroll
    for (int i = 0; i < 4; i++) {
      if (v[i].x > tau) { sp += v[i].x; cp += 1.f; }
      if (v[i].y > tau) { sp += v[i].y; cp += 1.f; }
      if (v[i].z > tau) { sp += v[i].z; cp += 1.f; }
      if (v[i].w > tau) { sp += v[i].w; cp += 1.f; }
    }
#pragma unroll
    for (int o = 32; o; o >>= 1) {
      sp += __shfl_xor(sp, o, 64);
      cp += __shfl_xor(cp, o, 64);
    }
    int ci = (int)cp;
    tau = (sp - 1.0f) / cp;
    if (ci == cprev) break;
    cprev = ci;
  }

  float4* xo4 = (float4*)(xold + (size_t)row * HID_);
  float4* xt4 = (float4*)(xtmp + (size_t)row * HID_);
  h4* xh4 = (h4*)(xth + (size_t)row * HID_);
#pragma unroll
  for (int i = 0; i < 4; i++) {
    float4 xn = make_float4(fmaxf(v[i].x - tau, 0.f), fmaxf(v[i].y - tau, 0.f),
                            fmaxf(v[i].z - tau, 0.f), fmaxf(v[i].w - tau, 0.f));
    float4 xt = xn;
    if (mom > 0.f) {
      float4 xo = xo4[lane + 64 * i];
      xt.x = xn.x + mom * (xn.x - xo.x);
      xt.y = xn.y + mom * (xn.y - xo.y);
      xt.z = xn.z + mom * (xn.z - xo.z);
      xt.w = xn.w + mom * (xn.w - xo.w);
    }
    xo4[lane + 64 * i] = xn;
    xt4[lane + 64 * i] = xt;
    h4 hv;
    hv[0] = (_Float16)xt.x; hv[1] = (_Float16)xt.y;
    hv[2] = (_Float16)xt.z; hv[3] = (_Float16)xt.w;
    xh4[lane + 64 * i] = hv;
  }
}

// ---------------------------------------------------------------------------
extern "C" void kernel_launch(void* const* d_in, const int* in_sizes, int n_in,
                              void* d_out, int out_size, void* d_ws, size_t ws_size,
                              hipStream_t stream) {
  (void)in_sizes; (void)n_in; (void)out_size; (void)ws_size;
  const float* y      = (const float*)d_in[0];  // [2048,512]
  const float* W      = (const float*)d_in[1];  // [1024,512]
  const float* step_p = (const float*)d_in[2];  // scalar
  float* out = (float*)d_out;                   // [2048,512]

  float* ws = (float*)d_ws;
  float* Cb = ws;                        // 2M f32
  float* z  = Cb + 2097152;              // 2M f32
  float* xt = z + 2097152;               // 2M f32
  float* xo = xt + 2097152;              // 2M f32
  float* dG = xo + 2097152;              // 1024 f32 (pad 1024)
  _Float16* Gh  = (_Float16*)(dG + 1024);  // 1M h
  _Float16* yh  = Gh + 1048576;            // 1M h
  _Float16* yl  = yh + 1048576;            // 1M h
  _Float16* Wh  = yl + 1048576;            // 512K h
  _Float16* Wl  = Wh + 524288;             // 512K h
  _Float16* WTh = Wl + 524288;             // 512K h
  _Float16* WTl = WTh + 524288;            // 512K h
  // aliases (lifetime-disjoint):
  _Float16* xth = yh;           // x_tmp fp16 (2M h) over yh+yl (dead after C)
  _Float16* xoh = (_Float16*)z; // x_new hi (2M h) over z (dead after last layer)
  _Float16* xol = xoh + 2097152;

  dim3 blk(256);
  // input splits
  split_hl<<<dim3(BATCH_ * IN_ / 4 / 256), blk, 0, stream>>>(y, yh, yl);
  split_hl<<<dim3(HID_ * IN_ / 4 / 256), blk, 0, stream>>>(W, Wh, Wl);
  transpose_split<<<dim3(IN_ / 32, HID_ / 32), dim3(32, 8), 0, stream>>>(W, WTh, WTl);

  // Gh = fp16(Wh @ Wh^T), dG = diag (f32)   [single pass; feeds fp16 anyway]
  hgemm_nt<H_GH><<<dim3(HID_ / 64, HID_ / 64), blk, 0, stream>>>(
      Wh, Wh, nullptr, nullptr, nullptr, nullptr, 1, IN_ / 64,
      nullptr, Gh, dG, HID_, IN_);
  // Cb = 0.1*dG[n] - 1.2*(y @ W^T)  via split-fp16 (3 passes)
  // (P*||y||^2 row-const dropped: simplex projection is shift-invariant)
  hgemm_nt<H_C><<<dim3(HID_ / 64, BATCH_ / 64), blk, 0, stream>>>(
      yh, Wh, yl, Wh, yh, Wl, 3, IN_ / 64, Cb, nullptr, dG, HID_, IN_);

  // layer 0: z = -step*C folded into sparsemax; mom = 0
  sparsemax_w<<<dim3(BATCH_ / 4), blk, 0, stream>>>(Cb, step_p, xo, xt, xth, 0.f);

  for (int l = 1; l < NL_; ++l) {
    hmma_z<<<dim3(HID_ / 64, BATCH_ / 64), blk, 0, stream>>>(
        xth, Gh, xt, Cb, z, step_p, BATCH_, HID_, HID_);
    float mom = (float)l / ((float)l + 3.0f);
    sparsemax_w<<<dim3(BATCH_ / 4), blk, 0, stream>>>(z, nullptr, xo, xt, xth, mom);
  }

  // decode: out = x_new @ W = x_new @ WT^T  via split-fp16 (3 passes)
  split_hl<<<dim3(BATCH_ * HID_ / 4 / 256), blk, 0, stream>>>(xo, xoh, xol);
  hgemm_nt<H_OUT><<<dim3(IN_ / 64, BATCH_ / 64), blk, 0, stream>>>(
      xoh, WTh, xol, WTh, xoh, WTl, 3, HID_ / 64,
      out, nullptr, nullptr, IN_, HID_);
}